// Round 3
// baseline (316.924 us; speedup 1.0000x reference)
//
#include <hip/hip_runtime.h>

// SelfAttention3D: B=4, C=128, N=16^3=4096, Cqk=16.
// R7: R5 structure (512 blocks x 8 waves, 32q/block, 512 keys/wave,
// reg-staged V + K ping-pong) with the LDS-P round-trip replaced by
// register-resident P via swapped QK^T (T12):
//   s = mfma(K, Q) -> lane holds P[key=4g+r][q=l15]
//   v_cvt_pk_bf16_f32 packs pairs; 2 cndmask + 4 shfl(bpermute) build each
//   PV A-fragment in-register. No ds_write/ds_read for P, no bank
//   conflicts, ~100 fewer VALU ops/iter, shorter dep chain.
// L is accumulated per-q-column (lane-local), reduced with 2 shfl_xor and
// transposed back to the (g,r) layout with 4 shfls per q-half.

typedef __attribute__((ext_vector_type(8))) short short8;
typedef __attribute__((ext_vector_type(4))) float f32x4;
typedef __attribute__((ext_vector_type(4))) unsigned int u32x4;

#define NTOK 4096
#define CDIM 128

__device__ __forceinline__ unsigned short f2bf(float f) {
  unsigned int u = __float_as_uint(f);
  return (unsigned short)((u + 0x7fffu + ((u >> 16) & 1u)) >> 16);
}

// ---------------------------------------------------------------------------
// Projection (unchanged from R5): q,k,v channel-GEMMs, bf16 outputs.
// qb,kb: [B][N][16] row per token; vb: tiled layout (see attn).
// ---------------------------------------------------------------------------
__global__ __launch_bounds__(256) void sa3d_proj(
    const float* __restrict__ x,
    const float* __restrict__ Wq, const float* __restrict__ bq,
    const float* __restrict__ Wk, const float* __restrict__ bk,
    const float* __restrict__ Wv, const float* __restrict__ bv,
    unsigned short* __restrict__ qb, unsigned short* __restrict__ kb,
    unsigned short* __restrict__ vb)
{
  __shared__ unsigned short Wl[160 * 136];
  __shared__ unsigned short xT[64 * 136];
  const int tid = threadIdx.x;
  const int b = (blockIdx.x & 7) >> 1;
  const int nt = ((blockIdx.x >> 3) << 1) | (blockIdx.x & 1);  // [0,64)
  const int n0 = nt << 6;

  for (int i = 0; i < 80; ++i) {
    int idx = i * 256 + tid;
    int o = idx >> 7, c = idx & 127;
    float wv;
    if (o < 16)      wv = Wq[o * 128 + c];
    else if (o < 32) wv = Wk[(o - 16) * 128 + c];
    else             wv = Wv[(o - 32) * 128 + c];
    Wl[o * 136 + c] = f2bf(wv);
  }
  {
    int nn = tid & 63, cg = tid >> 6;
    const float* xp = x + (size_t)b * CDIM * NTOK + n0 + nn;
    for (int cp = 0; cp < 16; ++cp) {
      int c = cg * 32 + cp * 2;
      float v0 = xp[(size_t)c * NTOK];
      float v1 = xp[(size_t)(c + 1) * NTOK];
      *(unsigned int*)&xT[nn * 136 + c] =
          (unsigned int)f2bf(v0) | ((unsigned int)f2bf(v1) << 16);
    }
  }
  __syncthreads();

  const int w = tid >> 6, lane = tid & 63;
  const int l15 = lane & 15, g = lane >> 4;

  short8 bfr[4];
#pragma unroll
  for (int ks = 0; ks < 4; ++ks)
    bfr[ks] = *(const short8*)&xT[(w * 16 + l15) * 136 + ks * 32 + g * 8];

  const int n = n0 + w * 16 + l15;
#pragma unroll
  for (int ot = 0; ot < 10; ++ot) {
    f32x4 acc = {};
#pragma unroll
    for (int ks = 0; ks < 4; ++ks) {
      short8 af = *(const short8*)&Wl[(ot * 16 + l15) * 136 + ks * 32 + g * 8];
      acc = __builtin_amdgcn_mfma_f32_16x16x32_bf16(af, bfr[ks], acc, 0, 0, 0);
    }
    int ob = ot * 16 + 4 * g;
    if (ot == 0) {
      unsigned int p0 = (unsigned int)f2bf(acc[0] + bq[ob]) |
                        ((unsigned int)f2bf(acc[1] + bq[ob + 1]) << 16);
      unsigned int p1 = (unsigned int)f2bf(acc[2] + bq[ob + 2]) |
                        ((unsigned int)f2bf(acc[3] + bq[ob + 3]) << 16);
      unsigned int* d = (unsigned int*)&qb[((size_t)b * NTOK + n) * 16 + ob];
      d[0] = p0; d[1] = p1;
    } else if (ot == 1) {
      int o2 = ob - 16;
      unsigned int p0 = (unsigned int)f2bf(acc[0] + bk[o2]) |
                        ((unsigned int)f2bf(acc[1] + bk[o2 + 1]) << 16);
      unsigned int p1 = (unsigned int)f2bf(acc[2] + bk[o2 + 2]) |
                        ((unsigned int)f2bf(acc[3] + bk[o2 + 3]) << 16);
      unsigned int* d = (unsigned int*)&kb[((size_t)b * NTOK + n) * 16 + o2];
      d[0] = p0; d[1] = p1;
    } else {
#pragma unroll
      for (int r = 0; r < 4; ++r) {
        int o = ob + r - 32;  // channel c in [0,128)
        // tiled V: elem(c,m) = (c>>4)*65536 + (m>>5)*512 + ((m>>3)&3)*128
        //                      + (c&15)*8 + (m&7)
        size_t eidx = (size_t)(o >> 4) * 65536 + (size_t)(n >> 5) * 512 +
                      (size_t)((n >> 3) & 3) * 128 + (o & 15) * 8 + (n & 7);
        vb[(size_t)b * (CDIM * NTOK) + eidx] = f2bf(acc[r] + bv[o]);
      }
    }
  }
}

// ---------------------------------------------------------------------------
// Flash attention. 512 blocks x 512 threads (8 waves), no in-loop barriers.
// Block: batch b=(bid&7)>>1 (XCD-pinned), 32 queries; wave w owns keys
// [w*512,(w+1)*512). Per iter: vf[16] register-staged V (coalesced 1KB
// loads), K ping-pong prefetch, REGISTER-resident P (swapped QK + shuffle).
// End: LDS tree-reduce of 8 waves' (acc,L), wave-0 epilogue gamma*acc/L + x.
// ---------------------------------------------------------------------------
__global__ __launch_bounds__(512, 4) void sa3d_attn(
    const unsigned short* __restrict__ qb, const unsigned short* __restrict__ kb,
    const unsigned short* __restrict__ vb,
    const float* __restrict__ x, const float* __restrict__ gamma,
    float* __restrict__ out)
{
  // LDS: [0,65536): 4 reduce slots of 16 KB (used only after the loop)
  //      [65536,66560): L reduce area, 4 slots x 32 floats
  __shared__ __align__(16) unsigned char smem[66560];

  const int tid = threadIdx.x;
  const int w = tid >> 6, lane = tid & 63;
  const int l15 = lane & 15, g = lane >> 4;
  const int b = (blockIdx.x & 7) >> 1;
  const int qt = ((blockIdx.x >> 3) << 1) | (blockIdx.x & 1);  // [0,128)
  const int q0 = qt << 5;

  float* LDp = (float*)(smem + 65536);

  const unsigned short* qbase = qb + (size_t)b * NTOK * 16;
  const unsigned short* kbase = kb + (size_t)b * NTOK * 16;
  const unsigned short* vbase = vb + (size_t)b * CDIM * NTOK;

  short8 aq[2] = {short8{}, short8{}};
#pragma unroll
  for (int qh = 0; qh < 2; ++qh)
    if (g < 2)
      aq[qh] = *(const short8*)&qbase[(size_t)(q0 + qh * 16 + l15) * 16 + g * 8];

  f32x4 acc[16];  // [qh*8 + ct]
#pragma unroll
  for (int i = 0; i < 16; ++i) acc[i] = (f32x4){};
  float Lq[2] = {0.f, 0.f};  // per-lane: sum of exp over this lane's keys,
                             // for q-column l15 (q-half qh)

  const int kv0 = w << 9;  // 512 keys per wave
  const bool hi32 = lane >= 32;                // g' >> 1
  const int srcb = l15 + ((g & 1) << 5);       // shuffle source base lane
  short8 pa[2];

  // K prefetch for tile 0
  short8 kfa[4], kfb[4];
#pragma unroll
  for (int kt = 0; kt < 4; ++kt) {
    kfa[kt] = short8{};
    if (g < 2)
      kfa[kt] = *(const short8*)&kbase[(size_t)(kv0 + kt * 16 + l15) * 16 + g * 8];
  }

  // One KV-tile iteration (64 keys): V reg-stage -> K prefetch ->
  // per 32-key half: swapped QK -> exp -> cvt_pk -> shuffle-exchange -> PV.
  // s = mfma(K,Q): lane(l15,g) reg r = S[key=16*kt+4g+r][q=l15].
  // PV A-frag word w for lane-group g': reg c[g'>>1][w&1] from lane
  // l15 + 16*(2*(g'&1) + (w>>1)).
#define SA_ITER(T, KC, KN)                                                    \
  {                                                                           \
    const int m0 = kv0 + ((T) << 6);                                          \
    const int mb5 = m0 >> 5;                                                  \
    short8 vf[16];                                                            \
    _Pragma("unroll") for (int ch = 0; ch < 2; ++ch)                          \
      _Pragma("unroll") for (int ct = 0; ct < 8; ++ct)                        \
        vf[ch * 8 + ct] = *(const short8*)&vbase[(size_t)ct * 65536 +         \
                                                 (size_t)(mb5 + ch) * 512 +   \
                                                 g * 128 + l15 * 8];          \
    const int mn = kv0 + (((T) + 1 < 8 ? (T) + 1 : 0) << 6);                  \
    _Pragma("unroll") for (int kt = 0; kt < 4; ++kt) {                        \
      KN[kt] = short8{};                                                      \
      if (g < 2)                                                              \
        KN[kt] = *(const short8*)&kbase[(size_t)(mn + kt * 16 + l15) * 16 +   \
                                        g * 8];                               \
    }                                                                         \
    _Pragma("unroll") for (int hc = 0; hc < 2; ++hc) {                        \
      unsigned int cpk[2][2][2]; /* [qh][kt2][pair] */                        \
      _Pragma("unroll") for (int kt2 = 0; kt2 < 2; ++kt2) {                   \
        _Pragma("unroll") for (int qh = 0; qh < 2; ++qh) {                    \
          f32x4 z = {};                                                       \
          f32x4 s = __builtin_amdgcn_mfma_f32_16x16x32_bf16(                  \
              KC[hc * 2 + kt2], aq[qh], z, 0, 0, 0);                          \
          float e0 = __expf(s[0]), e1 = __expf(s[1]);                         \
          float e2 = __expf(s[2]), e3 = __expf(s[3]);                         \
          Lq[qh] += (e0 + e1) + (e2 + e3);                                    \
          asm("v_cvt_pk_bf16_f32 %0, %1, %2"                                  \
              : "=v"(cpk[qh][kt2][0]) : "v"(e0), "v"(e1));                    \
          asm("v_cvt_pk_bf16_f32 %0, %1, %2"                                  \
              : "=v"(cpk[qh][kt2][1]) : "v"(e2), "v"(e3));                    \
        }                                                                     \
      }                                                                       \
      _Pragma("unroll") for (int qh = 0; qh < 2; ++qh) {                      \
        unsigned int selA = hi32 ? cpk[qh][1][0] : cpk[qh][0][0];             \
        unsigned int selB = hi32 ? cpk[qh][1][1] : cpk[qh][0][1];             \
        unsigned int w0 = (unsigned int)__shfl((int)selA, srcb);              \
        unsigned int w1 = (unsigned int)__shfl((int)selB, srcb);              \
        unsigned int w2 = (unsigned int)__shfl((int)selA, srcb + 16);         \
        unsigned int w3 = (unsigned int)__shfl((int)selB, srcb + 16);         \
        u32x4 pw = {w0, w1, w2, w3};                                          \
        pa[qh] = *(short8*)&pw;                                               \
      }                                                                       \
      _Pragma("unroll") for (int ct = 0; ct < 8; ++ct) {                      \
        acc[ct] = __builtin_amdgcn_mfma_f32_16x16x32_bf16(                    \
            pa[0], vf[hc * 8 + ct], acc[ct], 0, 0, 0);                        \
        acc[8 + ct] = __builtin_amdgcn_mfma_f32_16x16x32_bf16(                \
            pa[1], vf[hc * 8 + ct], acc[8 + ct], 0, 0, 0);                    \
      }                                                                       \
    }                                                                         \
  }

  for (int tt = 0; tt < 4; ++tt) {
    SA_ITER(tt * 2, kfa, kfb);
    SA_ITER(tt * 2 + 1, kfb, kfa);
  }
#undef SA_ITER

  // L reduce: sum the 4 g-groups (all lanes then hold L[q=l15]), then
  // transpose into the (g,r) layout the cross-wave reduce expects.
  float Lp[2][4];
#pragma unroll
  for (int qh = 0; qh < 2; ++qh) {
    float v = Lq[qh];
    v += __shfl_xor(v, 16);
    v += __shfl_xor(v, 32);
#pragma unroll
    for (int r = 0; r < 4; ++r)
      Lp[qh][r] = __shfl(v, 4 * g + r);
  }

  // cross-wave tree reduce: 8 -> 4 -> 2 -> 1 (XOR-swizzled 256B rows)
  const int rowb = lane * 256;
  const int sw = (l15) << 4;

#define ACC_STORE(i)                                                        \
  {                                                                         \
    char* base = (char*)smem + (i) * 16384 + rowb;                          \
    _Pragma("unroll") for (int j = 0; j < 16; ++j)                          \
        *(f32x4*)(base + ((j * 16) ^ sw)) = acc[j];                         \
    if (l15 == 0) {                                                         \
      _Pragma("unroll") for (int qh = 0; qh < 2; ++qh)                      \
          _Pragma("unroll") for (int r = 0; r < 4; ++r)                     \
              LDp[(i) * 32 + qh * 16 + 4 * g + r] = Lp[qh][r];              \
    }                                                                       \
  }
#define ACC_ADD(i)                                                          \
  {                                                                         \
    char* base = (char*)smem + (i) * 16384 + rowb;                          \
    _Pragma("unroll") for (int j = 0; j < 16; ++j)                          \
        acc[j] += *(const f32x4*)(base + ((j * 16) ^ sw));                  \
    _Pragma("unroll") for (int qh = 0; qh < 2; ++qh)                        \
        _Pragma("unroll") for (int r = 0; r < 4; ++r)                       \
            Lp[qh][r] += LDp[(i) * 32 + qh * 16 + 4 * g + r];               \
  }

  __syncthreads();
  if (w >= 4) ACC_STORE(w - 4);
  __syncthreads();
  if (w < 4) ACC_ADD(w);
  __syncthreads();
  if (w == 2 || w == 3) ACC_STORE(w - 2);
  __syncthreads();
  if (w < 2) ACC_ADD(w);
  __syncthreads();
  if (w == 1) ACC_STORE(0);
  __syncthreads();

  if (w == 0) {
    ACC_ADD(0);
    const float ga = gamma[0];
    float inv[2][4];
#pragma unroll
    for (int qh = 0; qh < 2; ++qh)
#pragma unroll
      for (int r = 0; r < 4; ++r) inv[qh][r] = 1.0f / Lp[qh][r];

    const float* xb = x + (size_t)b * CDIM * NTOK;
    float* ob = out + (size_t)b * CDIM * NTOK;
#pragma unroll
    for (int qh = 0; qh < 2; ++qh)
#pragma unroll
      for (int ct = 0; ct < 8; ++ct) {
        int c = ct * 16 + l15;
        size_t idx = (size_t)c * NTOK + q0 + qh * 16 + 4 * g;
        f32x4 xv = *(const f32x4*)&xb[idx];
        f32x4 o;
#pragma unroll
        for (int r = 0; r < 4; ++r)
          o[r] = ga * acc[qh * 8 + ct][r] * inv[qh][r] + xv[r];
        *(f32x4*)&ob[idx] = o;
      }
  }
}

extern "C" void kernel_launch(void* const* d_in, const int* in_sizes, int n_in,
                              void* d_out, int out_size, void* d_ws, size_t ws_size,
                              hipStream_t stream) {
  const float* x     = (const float*)d_in[0];
  const float* Wq    = (const float*)d_in[1];
  const float* bq    = (const float*)d_in[2];
  const float* Wk    = (const float*)d_in[3];
  const float* bk    = (const float*)d_in[4];
  const float* Wv    = (const float*)d_in[5];
  const float* bv    = (const float*)d_in[6];
  const float* gamma = (const float*)d_in[7];

  unsigned short* qb = (unsigned short*)d_ws;          // 512 KB
  unsigned short* kb = qb + (size_t)4 * NTOK * 16;     // 512 KB
  unsigned short* vb = kb + (size_t)4 * NTOK * 16;     // 4 MB (tiled layout)
  float* outp = (float*)d_out;

  sa3d_proj<<<dim3(256), dim3(256), 0, stream>>>(x, Wq, bq, Wk, bk, Wv, bv,
                                                 qb, kb, vb);
  sa3d_attn<<<dim3(512), dim3(512), 0, stream>>>(qb, kb, vb, x, gamma, outp);
}

// Round 4
// 147.255 us; speedup vs baseline: 2.1522x; 2.1522x over previous
//
#include <hip/hip_runtime.h>

// SelfAttention3D: B=4, C=128, N=16^3=4096, Cqk=16.
// R8: R5 skeleton (512 blocks x 8 waves, 32q/block, 512 keys/wave, LDS P,
// reg-staged V) with:
//  - P software-pipelined one tile ahead, double-buffered per-wave LDS:
//    iter t: read P(t) at top (written t-1) -> V(t) loads -> produce P(t+1)
//    (QK+exp) -> K(t+2) prefetch -> PV(t). No per-iter write->read drain.
//  - launch_bounds(512,2), live set ~200 VGPR (2 waves/SIMD tier): V loads
//    stay hoisted at iter top instead of being serialized into PV.
//  - V re-tiled contiguously: [b][tile(64keys)][frag(16)][1KB] -> all 16
//    V loads are uniform-base + constant-offset (address VALU ~0).
//  - v_cvt_pk_bf16_f32 replaces manual f2bf on the P path.
//  - Wq/bq pre-scaled by log2(e) in proj; attn uses exp2 (saves 32 muls/it).

typedef __attribute__((ext_vector_type(8))) short short8;
typedef __attribute__((ext_vector_type(4))) float f32x4;

#define NTOK 4096
#define CDIM 128
#define L2E 1.44269504088896340736f

__device__ __forceinline__ unsigned short f2bf(float f) {
  unsigned int u = __float_as_uint(f);
  return (unsigned short)((u + 0x7fffu + ((u >> 16) & 1u)) >> 16);
}

// ---------------------------------------------------------------------------
// Projection: q,k,v channel-GEMMs, bf16 outputs.
// qb,kb: [B][N][16] row per token. Q is pre-scaled by log2(e).
// vb tiled: elem(b,c,m) = b*524288 + (m>>6)*8192
//           + ((c>>4)*2 + ((m>>5)&1))*512 + ((m>>3)&3)*128 + (c&15)*8 + (m&7)
// ---------------------------------------------------------------------------
__global__ __launch_bounds__(256) void sa3d_proj(
    const float* __restrict__ x,
    const float* __restrict__ Wq, const float* __restrict__ bq,
    const float* __restrict__ Wk, const float* __restrict__ bk,
    const float* __restrict__ Wv, const float* __restrict__ bv,
    unsigned short* __restrict__ qb, unsigned short* __restrict__ kb,
    unsigned short* __restrict__ vb)
{
  __shared__ unsigned short Wl[160 * 136];
  __shared__ unsigned short xT[64 * 136];
  const int tid = threadIdx.x;
  const int b = (blockIdx.x & 7) >> 1;
  const int nt = ((blockIdx.x >> 3) << 1) | (blockIdx.x & 1);  // [0,64)
  const int n0 = nt << 6;

  for (int i = 0; i < 80; ++i) {
    int idx = i * 256 + tid;
    int o = idx >> 7, c = idx & 127;
    float wv;
    if (o < 16)      wv = Wq[o * 128 + c] * L2E;   // fold log2e into Q
    else if (o < 32) wv = Wk[(o - 16) * 128 + c];
    else             wv = Wv[(o - 32) * 128 + c];
    Wl[o * 136 + c] = f2bf(wv);
  }
  {
    int nn = tid & 63, cg = tid >> 6;
    const float* xp = x + (size_t)b * CDIM * NTOK + n0 + nn;
    for (int cp = 0; cp < 16; ++cp) {
      int c = cg * 32 + cp * 2;
      float v0 = xp[(size_t)c * NTOK];
      float v1 = xp[(size_t)(c + 1) * NTOK];
      *(unsigned int*)&xT[nn * 136 + c] =
          (unsigned int)f2bf(v0) | ((unsigned int)f2bf(v1) << 16);
    }
  }
  __syncthreads();

  const int w = tid >> 6, lane = tid & 63;
  const int l15 = lane & 15, g = lane >> 4;

  short8 bfr[4];
#pragma unroll
  for (int ks = 0; ks < 4; ++ks)
    bfr[ks] = *(const short8*)&xT[(w * 16 + l15) * 136 + ks * 32 + g * 8];

  const int n = n0 + w * 16 + l15;
#pragma unroll
  for (int ot = 0; ot < 10; ++ot) {
    f32x4 acc = {};
#pragma unroll
    for (int ks = 0; ks < 4; ++ks) {
      short8 af = *(const short8*)&Wl[(ot * 16 + l15) * 136 + ks * 32 + g * 8];
      acc = __builtin_amdgcn_mfma_f32_16x16x32_bf16(af, bfr[ks], acc, 0, 0, 0);
    }
    int ob = ot * 16 + 4 * g;
    if (ot == 0) {
      unsigned int p0 = (unsigned int)f2bf(acc[0] + bq[ob] * L2E) |
                        ((unsigned int)f2bf(acc[1] + bq[ob + 1] * L2E) << 16);
      unsigned int p1 = (unsigned int)f2bf(acc[2] + bq[ob + 2] * L2E) |
                        ((unsigned int)f2bf(acc[3] + bq[ob + 3] * L2E) << 16);
      unsigned int* d = (unsigned int*)&qb[((size_t)b * NTOK + n) * 16 + ob];
      d[0] = p0; d[1] = p1;
    } else if (ot == 1) {
      int o2 = ob - 16;
      unsigned int p0 = (unsigned int)f2bf(acc[0] + bk[o2]) |
                        ((unsigned int)f2bf(acc[1] + bk[o2 + 1]) << 16);
      unsigned int p1 = (unsigned int)f2bf(acc[2] + bk[o2 + 2]) |
                        ((unsigned int)f2bf(acc[3] + bk[o2 + 3]) << 16);
      unsigned int* d = (unsigned int*)&kb[((size_t)b * NTOK + n) * 16 + o2];
      d[0] = p0; d[1] = p1;
    } else {
#pragma unroll
      for (int r = 0; r < 4; ++r) {
        int o = ob + r - 32;  // channel c in [0,128)
        size_t eidx = (size_t)(n >> 6) * 8192 +
                      (size_t)((o >> 4) * 2 + ((n >> 5) & 1)) * 512 +
                      (size_t)((n >> 3) & 3) * 128 + (o & 15) * 8 + (n & 7);
        vb[(size_t)b * (CDIM * NTOK) + eidx] = f2bf(acc[r] + bv[o]);
      }
    }
  }
}

// ---------------------------------------------------------------------------
// Flash attention. 512 blocks x 512 threads (8 waves), no in-loop barriers.
// Block: batch b=(bid&7)>>1 (XCD-pinned), 32 queries; wave w owns keys
// [w*512,(w+1)*512) = 8 tiles of 64. P pipelined one tile ahead through a
// per-wave double-buffered LDS region. K prefetched two tiles ahead.
// End: LDS tree-reduce of 8 waves' (acc,L), wave-0 epilogue gamma*acc/L + x.
// ---------------------------------------------------------------------------
__global__ __launch_bounds__(512, 2) void sa3d_attn(
    const unsigned short* __restrict__ qb, const unsigned short* __restrict__ kb,
    const unsigned short* __restrict__ vb,
    const float* __restrict__ x, const float* __restrict__ gamma,
    float* __restrict__ out)
{
  // LDS: [0,73728): 8 waves x 2 P buffers x (32 rows x 72 shorts = 4608 B)
  //      after loop (reuse): [0,65536) 4 reduce slots; [65536,66560) L area
  __shared__ __align__(16) unsigned char smem[73728];

  const int tid = threadIdx.x;
  const int w = tid >> 6, lane = tid & 63;
  const int l15 = lane & 15, g = lane >> 4;
  const int b = (blockIdx.x & 7) >> 1;
  const int qt = ((blockIdx.x >> 3) << 1) | (blockIdx.x & 1);  // [0,128)
  const int q0 = qt << 5;

  unsigned short* PLw = (unsigned short*)(smem + w * 9216);  // 2 x 2304 shorts
  float* LDp = (float*)(smem + 65536);

  const unsigned short* qbase = qb + (size_t)b * NTOK * 16;
  const unsigned short* kbase = kb + (size_t)b * NTOK * 16;
  const unsigned short* vbase = vb + (size_t)b * CDIM * NTOK;

  short8 aq[2] = {short8{}, short8{}};
#pragma unroll
  for (int qh = 0; qh < 2; ++qh)
    if (g < 2)
      aq[qh] = *(const short8*)&qbase[(size_t)(q0 + qh * 16 + l15) * 16 + g * 8];

  f32x4 acc[16];  // [qh*8 + ct]
#pragma unroll
  for (int i = 0; i < 16; ++i) acc[i] = (f32x4){};
  float Lp[2][4] = {{0.f, 0.f, 0.f, 0.f}, {0.f, 0.f, 0.f, 0.f}};

  const int kv0 = w << 9;                       // 512 keys per wave
  const int voff = g * 128 + l15 * 8;           // lane offset inside V frag
  const unsigned short* vtile = vbase + (size_t)(kv0 >> 6) * 8192;

  // K prefetch: kfa <- K(0), kfb <- K(1)
  short8 kfa[4], kfb[4];
#pragma unroll
  for (int kt = 0; kt < 4; ++kt) {
    kfa[kt] = short8{};
    kfb[kt] = short8{};
    if (g < 2) {
      kfa[kt] = *(const short8*)&kbase[(size_t)(kv0 + kt * 16 + l15) * 16 + g * 8];
      kfb[kt] = *(const short8*)&kbase[(size_t)(kv0 + 64 + kt * 16 + l15) * 16 + g * 8];
    }
  }

  // Produce P(TN) into LDS buf TN&1 from K fragments KC: QK -> exp2 ->
  // cvt_pk_bf16 -> 4 ds_write_b16 per (kt,qh).
#define SA_PRODUCE(TN, KC)                                                    \
  {                                                                           \
    const int pbn = ((TN) & 1) * 2304;                                        \
    _Pragma("unroll") for (int kt = 0; kt < 4; ++kt) {                        \
      _Pragma("unroll") for (int qh = 0; qh < 2; ++qh) {                      \
        f32x4 z = {};                                                         \
        f32x4 s = __builtin_amdgcn_mfma_f32_16x16x32_bf16(aq[qh], KC[kt],     \
                                                          z, 0, 0, 0);        \
        float e0 = __builtin_exp2f(s[0]);                                     \
        float e1 = __builtin_exp2f(s[1]);                                     \
        float e2 = __builtin_exp2f(s[2]);                                     \
        float e3 = __builtin_exp2f(s[3]);                                     \
        Lp[qh][0] += e0; Lp[qh][1] += e1;                                     \
        Lp[qh][2] += e2; Lp[qh][3] += e3;                                     \
        unsigned int pk0, pk1;                                                \
        asm("v_cvt_pk_bf16_f32 %0, %1, %2" : "=v"(pk0) : "v"(e0), "v"(e1));   \
        asm("v_cvt_pk_bf16_f32 %0, %1, %2" : "=v"(pk1) : "v"(e2), "v"(e3));   \
        const int rb = pbn + (qh * 16 + 4 * g) * 72 + kt * 16 + l15;          \
        PLw[rb]       = (unsigned short)pk0;                                  \
        PLw[rb + 72]  = (unsigned short)(pk0 >> 16);                          \
        PLw[rb + 144] = (unsigned short)pk1;                                  \
        PLw[rb + 216] = (unsigned short)(pk1 >> 16);                          \
      }                                                                       \
    }                                                                         \
  }

  // Iter T: read P(T) early -> V(T) loads -> produce P(T+1) from KC=K(T+1)
  // -> prefetch K(T+2) into KN (if PREF) -> PV(T).
#define SA_ITER(T, KC, KN, PREF)                                              \
  {                                                                           \
    const int pbo = ((T) & 1) * 2304;                                         \
    short8 pa[2][2];                                                          \
    _Pragma("unroll") for (int qh = 0; qh < 2; ++qh)                          \
      _Pragma("unroll") for (int ch = 0; ch < 2; ++ch)                        \
        pa[qh][ch] = *(const short8*)&PLw[pbo + (qh * 16 + l15) * 72 +        \
                                          ch * 32 + g * 8];                   \
    short8 vf[16];                                                            \
    {                                                                         \
      const unsigned short* vt = vtile + (size_t)(T) * 8192;                  \
      _Pragma("unroll") for (int ct = 0; ct < 8; ++ct)                        \
        _Pragma("unroll") for (int ch = 0; ch < 2; ++ch)                      \
          vf[ch * 8 + ct] = *(const short8*)&vt[(ct * 2 + ch) * 512 + voff];  \
    }                                                                         \
    SA_PRODUCE((T) + 1, KC);                                                  \
    if (PREF) {                                                               \
      _Pragma("unroll") for (int kt = 0; kt < 4; ++kt) {                      \
        KN[kt] = short8{};                                                    \
        if (g < 2)                                                            \
          KN[kt] = *(const short8*)&kbase[                                    \
              (size_t)(kv0 + (((T) + 2) << 6) + kt * 16 + l15) * 16 + g * 8]; \
      }                                                                       \
    }                                                                         \
    __builtin_amdgcn_s_setprio(1);                                            \
    _Pragma("unroll") for (int ch = 0; ch < 2; ++ch)                          \
      _Pragma("unroll") for (int ct = 0; ct < 8; ++ct) {                      \
        acc[ct] = __builtin_amdgcn_mfma_f32_16x16x32_bf16(                    \
            pa[0][ch], vf[ch * 8 + ct], acc[ct], 0, 0, 0);                    \
        acc[8 + ct] = __builtin_amdgcn_mfma_f32_16x16x32_bf16(                \
            pa[1][ch], vf[ch * 8 + ct], acc[8 + ct], 0, 0, 0);                \
      }                                                                       \
    __builtin_amdgcn_s_setprio(0);                                            \
  }

  // Tail iter: read P(T), V(T), PV only.
#define SA_TAIL(T)                                                            \
  {                                                                           \
    const int pbo = ((T) & 1) * 2304;                                         \
    short8 pa[2][2];                                                          \
    _Pragma("unroll") for (int qh = 0; qh < 2; ++qh)                          \
      _Pragma("unroll") for (int ch = 0; ch < 2; ++ch)                        \
        pa[qh][ch] = *(const short8*)&PLw[pbo + (qh * 16 + l15) * 72 +        \
                                          ch * 32 + g * 8];                   \
    short8 vf[16];                                                            \
    {                                                                         \
      const unsigned short* vt = vtile + (size_t)(T) * 8192;                  \
      _Pragma("unroll") for (int ct = 0; ct < 8; ++ct)                        \
        _Pragma("unroll") for (int ch = 0; ch < 2; ++ch)                      \
          vf[ch * 8 + ct] = *(const short8*)&vt[(ct * 2 + ch) * 512 + voff];  \
    }                                                                         \
    __builtin_amdgcn_s_setprio(1);                                            \
    _Pragma("unroll") for (int ch = 0; ch < 2; ++ch)                          \
      _Pragma("unroll") for (int ct = 0; ct < 8; ++ct) {                      \
        acc[ct] = __builtin_amdgcn_mfma_f32_16x16x32_bf16(                    \
            pa[0][ch], vf[ch * 8 + ct], acc[ct], 0, 0, 0);                    \
        acc[8 + ct] = __builtin_amdgcn_mfma_f32_16x16x32_bf16(                \
            pa[1][ch], vf[ch * 8 + ct], acc[8 + ct], 0, 0, 0);                \
      }                                                                       \
    __builtin_amdgcn_s_setprio(0);                                            \
  }

  SA_PRODUCE(0, kfa);
  SA_ITER(0, kfb, kfa, 1);
  SA_ITER(1, kfa, kfb, 1);
  SA_ITER(2, kfb, kfa, 1);
  SA_ITER(3, kfa, kfb, 1);
  SA_ITER(4, kfb, kfa, 1);
  SA_ITER(5, kfa, kfb, 1);
  SA_ITER(6, kfb, kfa, 0);
  SA_TAIL(7);
#undef SA_PRODUCE
#undef SA_ITER
#undef SA_TAIL

  // intra-wave L reduce over the 16 key-columns
#pragma unroll
  for (int qh = 0; qh < 2; ++qh)
#pragma unroll
    for (int r = 0; r < 4; ++r) {
      float v = Lp[qh][r];
      v += __shfl_xor(v, 1);
      v += __shfl_xor(v, 2);
      v += __shfl_xor(v, 4);
      v += __shfl_xor(v, 8);
      Lp[qh][r] = v;
    }

  // cross-wave tree reduce: 8 -> 4 -> 2 -> 1 (XOR-swizzled 256B rows)
  const int rowb = lane * 256;
  const int sw = (l15) << 4;

#define ACC_STORE(i)                                                        \
  {                                                                         \
    char* base = (char*)smem + (i) * 16384 + rowb;                          \
    _Pragma("unroll") for (int j = 0; j < 16; ++j)                          \
        *(f32x4*)(base + ((j * 16) ^ sw)) = acc[j];                         \
    if (l15 == 0) {                                                         \
      _Pragma("unroll") for (int qh = 0; qh < 2; ++qh)                      \
          _Pragma("unroll") for (int r = 0; r < 4; ++r)                     \
              LDp[(i) * 32 + qh * 16 + 4 * g + r] = Lp[qh][r];              \
    }                                                                       \
  }
#define ACC_ADD(i)                                                          \
  {                                                                         \
    char* base = (char*)smem + (i) * 16384 + rowb;                          \
    _Pragma("unroll") for (int j = 0; j < 16; ++j)                          \
        acc[j] += *(const f32x4*)(base + ((j * 16) ^ sw));                  \
    _Pragma("unroll") for (int qh = 0; qh < 2; ++qh)                        \
        _Pragma("unroll") for (int r = 0; r < 4; ++r)                       \
            Lp[qh][r] += LDp[(i) * 32 + qh * 16 + 4 * g + r];               \
  }

  __syncthreads();
  if (w >= 4) ACC_STORE(w - 4);
  __syncthreads();
  if (w < 4) ACC_ADD(w);
  __syncthreads();
  if (w == 2 || w == 3) ACC_STORE(w - 2);
  __syncthreads();
  if (w < 2) ACC_ADD(w);
  __syncthreads();
  if (w == 1) ACC_STORE(0);
  __syncthreads();

  if (w == 0) {
    ACC_ADD(0);
    const float ga = gamma[0];
    float inv[2][4];
#pragma unroll
    for (int qh = 0; qh < 2; ++qh)
#pragma unroll
      for (int r = 0; r < 4; ++r) inv[qh][r] = 1.0f / Lp[qh][r];

    const float* xb = x + (size_t)b * CDIM * NTOK;
    float* ob = out + (size_t)b * CDIM * NTOK;
#pragma unroll
    for (int qh = 0; qh < 2; ++qh)
#pragma unroll
      for (int ct = 0; ct < 8; ++ct) {
        int c = ct * 16 + l15;
        size_t idx = (size_t)c * NTOK + q0 + qh * 16 + 4 * g;
        f32x4 xv = *(const f32x4*)&xb[idx];
        f32x4 o;
#pragma unroll
        for (int r = 0; r < 4; ++r)
          o[r] = ga * acc[qh * 8 + ct][r] * inv[qh][r] + xv[r];
        *(f32x4*)&ob[idx] = o;
      }
  }
}

extern "C" void kernel_launch(void* const* d_in, const int* in_sizes, int n_in,
                              void* d_out, int out_size, void* d_ws, size_t ws_size,
                              hipStream_t stream) {
  const float* x     = (const float*)d_in[0];
  const float* Wq    = (const float*)d_in[1];
  const float* bq    = (const float*)d_in[2];
  const float* Wk    = (const float*)d_in[3];
  const float* bk    = (const float*)d_in[4];
  const float* Wv    = (const float*)d_in[5];
  const float* bv    = (const float*)d_in[6];
  const float* gamma = (const float*)d_in[7];

  unsigned short* qb = (unsigned short*)d_ws;          // 512 KB
  unsigned short* kb = qb + (size_t)4 * NTOK * 16;     // 512 KB
  unsigned short* vb = kb + (size_t)4 * NTOK * 16;     // 4 MB (tiled layout)
  float* outp = (float*)d_out;

  sa3d_proj<<<dim3(256), dim3(256), 0, stream>>>(x, Wq, bq, Wk, bk, Wv, bv,
                                                 qb, kb, vb);
  sa3d_attn<<<dim3(512), dim3(512), 0, stream>>>(qb, kb, vb, x, gamma, outp);
}

// Round 5
// 142.443 us; speedup vs baseline: 2.2249x; 1.0338x over previous
//
#include <hip/hip_runtime.h>

// SelfAttention3D: B=4, C=128, N=16^3=4096, Cqk=16.
// R9: R8's pipelined-P structure with the register peak cut to ~116 so the
// allocator's 128-reg target fits WITHOUT spilling (R6/R7/R8 all died to
// scratch spills; hipcc targets 512/(2*min_waves) regs and spills to get
// there). Changes vs R8:
//  - single kf buffer: K(t+2) reloaded into the SAME regs right after the
//    produce phase kills them (load->use gap ~1 iter, saves 16 regs).
//  - pa read per q-half (8 transient regs, not 16 persistent).
// Keeps: P double-buffered in per-wave LDS (write iter t, read top of t+1,
// no same-iter lgkm turnaround), exp2 w/ log2e folded into Q, contiguous
// 16KB V tiles (uniform-stepped base), cvt_pk bf16 packing, setprio on PV,
// no in-loop barriers.

typedef __attribute__((ext_vector_type(8))) short short8;
typedef __attribute__((ext_vector_type(4))) float f32x4;

#define NTOK 4096
#define CDIM 128
#define L2E 1.44269504088896340736f

__device__ __forceinline__ unsigned short f2bf(float f) {
  unsigned int u = __float_as_uint(f);
  return (unsigned short)((u + 0x7fffu + ((u >> 16) & 1u)) >> 16);
}

// ---------------------------------------------------------------------------
// Projection (unchanged from R8, harness-verified): q,k,v channel-GEMMs.
// qb,kb: [B][N][16] row per token. Q pre-scaled by log2(e).
// vb tiled: elem(b,c,m) = b*524288 + (m>>6)*8192
//           + ((c>>4)*2 + ((m>>5)&1))*512 + ((m>>3)&3)*128 + (c&15)*8 + (m&7)
// ---------------------------------------------------------------------------
__global__ __launch_bounds__(256) void sa3d_proj(
    const float* __restrict__ x,
    const float* __restrict__ Wq, const float* __restrict__ bq,
    const float* __restrict__ Wk, const float* __restrict__ bk,
    const float* __restrict__ Wv, const float* __restrict__ bv,
    unsigned short* __restrict__ qb, unsigned short* __restrict__ kb,
    unsigned short* __restrict__ vb)
{
  __shared__ unsigned short Wl[160 * 136];
  __shared__ unsigned short xT[64 * 136];
  const int tid = threadIdx.x;
  const int b = (blockIdx.x & 7) >> 1;
  const int nt = ((blockIdx.x >> 3) << 1) | (blockIdx.x & 1);  // [0,64)
  const int n0 = nt << 6;

  for (int i = 0; i < 80; ++i) {
    int idx = i * 256 + tid;
    int o = idx >> 7, c = idx & 127;
    float wv;
    if (o < 16)      wv = Wq[o * 128 + c] * L2E;   // fold log2e into Q
    else if (o < 32) wv = Wk[(o - 16) * 128 + c];
    else             wv = Wv[(o - 32) * 128 + c];
    Wl[o * 136 + c] = f2bf(wv);
  }
  {
    int nn = tid & 63, cg = tid >> 6;
    const float* xp = x + (size_t)b * CDIM * NTOK + n0 + nn;
    for (int cp = 0; cp < 16; ++cp) {
      int c = cg * 32 + cp * 2;
      float v0 = xp[(size_t)c * NTOK];
      float v1 = xp[(size_t)(c + 1) * NTOK];
      *(unsigned int*)&xT[nn * 136 + c] =
          (unsigned int)f2bf(v0) | ((unsigned int)f2bf(v1) << 16);
    }
  }
  __syncthreads();

  const int w = tid >> 6, lane = tid & 63;
  const int l15 = lane & 15, g = lane >> 4;

  short8 bfr[4];
#pragma unroll
  for (int ks = 0; ks < 4; ++ks)
    bfr[ks] = *(const short8*)&xT[(w * 16 + l15) * 136 + ks * 32 + g * 8];

  const int n = n0 + w * 16 + l15;
#pragma unroll
  for (int ot = 0; ot < 10; ++ot) {
    f32x4 acc = {};
#pragma unroll
    for (int ks = 0; ks < 4; ++ks) {
      short8 af = *(const short8*)&Wl[(ot * 16 + l15) * 136 + ks * 32 + g * 8];
      acc = __builtin_amdgcn_mfma_f32_16x16x32_bf16(af, bfr[ks], acc, 0, 0, 0);
    }
    int ob = ot * 16 + 4 * g;
    if (ot == 0) {
      unsigned int p0 = (unsigned int)f2bf(acc[0] + bq[ob] * L2E) |
                        ((unsigned int)f2bf(acc[1] + bq[ob + 1] * L2E) << 16);
      unsigned int p1 = (unsigned int)f2bf(acc[2] + bq[ob + 2] * L2E) |
                        ((unsigned int)f2bf(acc[3] + bq[ob + 3] * L2E) << 16);
      unsigned int* d = (unsigned int*)&qb[((size_t)b * NTOK + n) * 16 + ob];
      d[0] = p0; d[1] = p1;
    } else if (ot == 1) {
      int o2 = ob - 16;
      unsigned int p0 = (unsigned int)f2bf(acc[0] + bk[o2]) |
                        ((unsigned int)f2bf(acc[1] + bk[o2 + 1]) << 16);
      unsigned int p1 = (unsigned int)f2bf(acc[2] + bk[o2 + 2]) |
                        ((unsigned int)f2bf(acc[3] + bk[o2 + 3]) << 16);
      unsigned int* d = (unsigned int*)&kb[((size_t)b * NTOK + n) * 16 + o2];
      d[0] = p0; d[1] = p1;
    } else {
#pragma unroll
      for (int r = 0; r < 4; ++r) {
        int o = ob + r - 32;  // channel c in [0,128)
        size_t eidx = (size_t)(n >> 6) * 8192 +
                      (size_t)((o >> 4) * 2 + ((n >> 5) & 1)) * 512 +
                      (size_t)((n >> 3) & 3) * 128 + (o & 15) * 8 + (n & 7);
        vb[(size_t)b * (CDIM * NTOK) + eidx] = f2bf(acc[r] + bv[o]);
      }
    }
  }
}

// ---------------------------------------------------------------------------
// Flash attention. 512 blocks x 512 threads (8 waves), no in-loop barriers.
// Block: batch b=(bid&7)>>1 (XCD-pinned), 32 queries; wave w owns keys
// [w*512,(w+1)*512) = 8 tiles of 64. Per iter t:
//   read pa(qh0) from P[t&1] (written iter t-1) -> issue 16 V(t) loads ->
//   produce P(t+1) (QK+exp2+cvt_pk -> LDS buf (t+1)&1) using kf=K(t+1) ->
//   reload kf <- K(t+2) (same regs; dead after produce) ->
//   PV qh0 -> read pa(qh1) -> PV qh1.
// End: LDS tree-reduce of 8 waves' (acc,L), wave-0 epilogue gamma*acc/L + x.
// ---------------------------------------------------------------------------
__global__ __launch_bounds__(512, 2) void sa3d_attn(
    const unsigned short* __restrict__ qb, const unsigned short* __restrict__ kb,
    const unsigned short* __restrict__ vb,
    const float* __restrict__ x, const float* __restrict__ gamma,
    float* __restrict__ out)
{
  // LDS: [0,73728): 8 waves x 2 P buffers x (32 rows x 72 shorts = 4608 B)
  //      after loop (reuse): [0,65536) 4 reduce slots; [65536,66560) L area
  __shared__ __align__(16) unsigned char smem[73728];

  const int tid = threadIdx.x;
  const int w = tid >> 6, lane = tid & 63;
  const int l15 = lane & 15, g = lane >> 4;
  const int b = (blockIdx.x & 7) >> 1;
  const int qt = ((blockIdx.x >> 3) << 1) | (blockIdx.x & 1);  // [0,128)
  const int q0 = qt << 5;

  unsigned short* PLw = (unsigned short*)(smem + w * 9216);  // 2 x 2304 shorts
  float* LDp = (float*)(smem + 65536);

  const unsigned short* qbase = qb + (size_t)b * NTOK * 16;
  const unsigned short* kbase = kb + (size_t)b * NTOK * 16;
  const unsigned short* vbase = vb + (size_t)b * CDIM * NTOK;

  short8 aq[2] = {short8{}, short8{}};
#pragma unroll
  for (int qh = 0; qh < 2; ++qh)
    if (g < 2)
      aq[qh] = *(const short8*)&qbase[(size_t)(q0 + qh * 16 + l15) * 16 + g * 8];

  f32x4 acc[16];  // [qh*8 + ct]
#pragma unroll
  for (int i = 0; i < 16; ++i) acc[i] = (f32x4){};
  float Lp[2][4] = {{0.f, 0.f, 0.f, 0.f}, {0.f, 0.f, 0.f, 0.f}};

  const int kv0 = w << 9;                       // 512 keys per wave
  const int voff = g * 128 + l15 * 8;           // lane offset inside V frag
  const unsigned short* vtile = vbase + (size_t)(kv0 >> 6) * 8192;

  short8 kf[4];  // single K buffer, reloaded after each produce

#define LOADK(TT)                                                             \
  {                                                                           \
    _Pragma("unroll") for (int kt = 0; kt < 4; ++kt) {                        \
      kf[kt] = short8{};                                                      \
      if (g < 2)                                                              \
        kf[kt] = *(const short8*)&kbase[                                      \
            (size_t)(kv0 + ((TT) << 6) + kt * 16 + l15) * 16 + g * 8];        \
    }                                                                         \
  }

  // Produce P(TN) into LDS buf TN&1 from kf: QK -> exp2 -> cvt_pk -> 4 b16.
#define SA_PRODUCE(TN)                                                        \
  {                                                                           \
    const int pbn = ((TN) & 1) * 2304;                                        \
    _Pragma("unroll") for (int kt = 0; kt < 4; ++kt) {                        \
      _Pragma("unroll") for (int qh = 0; qh < 2; ++qh) {                      \
        f32x4 z = {};                                                         \
        f32x4 s = __builtin_amdgcn_mfma_f32_16x16x32_bf16(aq[qh], kf[kt],     \
                                                          z, 0, 0, 0);        \
        float e0 = __builtin_exp2f(s[0]);                                     \
        float e1 = __builtin_exp2f(s[1]);                                     \
        float e2 = __builtin_exp2f(s[2]);                                     \
        float e3 = __builtin_exp2f(s[3]);                                     \
        Lp[qh][0] += e0; Lp[qh][1] += e1;                                     \
        Lp[qh][2] += e2; Lp[qh][3] += e3;                                     \
        unsigned int pk0, pk1;                                                \
        asm("v_cvt_pk_bf16_f32 %0, %1, %2" : "=v"(pk0) : "v"(e0), "v"(e1));   \
        asm("v_cvt_pk_bf16_f32 %0, %1, %2" : "=v"(pk1) : "v"(e2), "v"(e3));   \
        const int rb = pbn + (qh * 16 + 4 * g) * 72 + kt * 16 + l15;          \
        PLw[rb]       = (unsigned short)pk0;                                  \
        PLw[rb + 72]  = (unsigned short)(pk0 >> 16);                          \
        PLw[rb + 144] = (unsigned short)pk1;                                  \
        PLw[rb + 216] = (unsigned short)(pk1 >> 16);                          \
      }                                                                       \
    }                                                                         \
  }

  // Iter T: pa(qh0) -> V(T) -> produce P(T+1) (if PROD) -> kf<-K(T+2)
  // (if PREF) -> PV qh0 -> pa(qh1) -> PV qh1.
#define SA_ITER(T, PROD, PREF)                                                \
  {                                                                           \
    const int pbo = ((T) & 1) * 2304;                                         \
    short8 pa0[2];                                                            \
    _Pragma("unroll") for (int ch = 0; ch < 2; ++ch)                          \
      pa0[ch] = *(const short8*)&PLw[pbo + l15 * 72 + ch * 32 + g * 8];       \
    short8 vf[16];                                                            \
    {                                                                         \
      const unsigned short* vt = vtile + (size_t)(T) * 8192;                  \
      _Pragma("unroll") for (int f = 0; f < 16; ++f)                          \
        vf[f] = *(const short8*)&vt[f * 512 + voff];                          \
    }                                                                         \
    if (PROD) SA_PRODUCE((T) + 1);                                            \
    if (PREF) LOADK((T) + 2);                                                 \
    __builtin_amdgcn_s_setprio(1);                                            \
    _Pragma("unroll") for (int ch = 0; ch < 2; ++ch)                          \
      _Pragma("unroll") for (int ct = 0; ct < 8; ++ct)                        \
        acc[ct] = __builtin_amdgcn_mfma_f32_16x16x32_bf16(                    \
            pa0[ch], vf[ct * 2 + ch], acc[ct], 0, 0, 0);                      \
    __builtin_amdgcn_s_setprio(0);                                            \
    short8 pa1[2];                                                            \
    _Pragma("unroll") for (int ch = 0; ch < 2; ++ch)                          \
      pa1[ch] = *(const short8*)&PLw[pbo + (16 + l15) * 72 + ch * 32 + g * 8];\
    __builtin_amdgcn_s_setprio(1);                                            \
    _Pragma("unroll") for (int ch = 0; ch < 2; ++ch)                          \
      _Pragma("unroll") for (int ct = 0; ct < 8; ++ct)                        \
        acc[8 + ct] = __builtin_amdgcn_mfma_f32_16x16x32_bf16(                \
            pa1[ch], vf[ct * 2 + ch], acc[8 + ct], 0, 0, 0);                  \
    __builtin_amdgcn_s_setprio(0);                                            \
  }

  LOADK(0);
  SA_PRODUCE(0);
  LOADK(1);
  SA_ITER(0, 1, 1);
  SA_ITER(1, 1, 1);
  SA_ITER(2, 1, 1);
  SA_ITER(3, 1, 1);
  SA_ITER(4, 1, 1);
  SA_ITER(5, 1, 1);
  SA_ITER(6, 1, 0);
  SA_ITER(7, 0, 0);
#undef SA_PRODUCE
#undef SA_ITER
#undef LOADK

  // intra-wave L reduce over the 16 key-columns
#pragma unroll
  for (int qh = 0; qh < 2; ++qh)
#pragma unroll
    for (int r = 0; r < 4; ++r) {
      float v = Lp[qh][r];
      v += __shfl_xor(v, 1);
      v += __shfl_xor(v, 2);
      v += __shfl_xor(v, 4);
      v += __shfl_xor(v, 8);
      Lp[qh][r] = v;
    }

  // cross-wave tree reduce: 8 -> 4 -> 2 -> 1 (XOR-swizzled 256B rows)
  const int rowb = lane * 256;
  const int sw = (l15) << 4;

#define ACC_STORE(i)                                                        \
  {                                                                         \
    char* base = (char*)smem + (i) * 16384 + rowb;                          \
    _Pragma("unroll") for (int j = 0; j < 16; ++j)                          \
        *(f32x4*)(base + ((j * 16) ^ sw)) = acc[j];                         \
    if (l15 == 0) {                                                         \
      _Pragma("unroll") for (int qh = 0; qh < 2; ++qh)                      \
          _Pragma("unroll") for (int r = 0; r < 4; ++r)                     \
              LDp[(i) * 32 + qh * 16 + 4 * g + r] = Lp[qh][r];              \
    }                                                                       \
  }
#define ACC_ADD(i)                                                          \
  {                                                                         \
    char* base = (char*)smem + (i) * 16384 + rowb;                          \
    _Pragma("unroll") for (int j = 0; j < 16; ++j)                          \
        acc[j] += *(const f32x4*)(base + ((j * 16) ^ sw));                  \
    _Pragma("unroll") for (int qh = 0; qh < 2; ++qh)                        \
        _Pragma("unroll") for (int r = 0; r < 4; ++r)                       \
            Lp[qh][r] += LDp[(i) * 32 + qh * 16 + 4 * g + r];               \
  }

  __syncthreads();
  if (w >= 4) ACC_STORE(w - 4);
  __syncthreads();
  if (w < 4) ACC_ADD(w);
  __syncthreads();
  if (w == 2 || w == 3) ACC_STORE(w - 2);
  __syncthreads();
  if (w < 2) ACC_ADD(w);
  __syncthreads();
  if (w == 1) ACC_STORE(0);
  __syncthreads();

  if (w == 0) {
    ACC_ADD(0);
    const float ga = gamma[0];
    float inv[2][4];
#pragma unroll
    for (int qh = 0; qh < 2; ++qh)
#pragma unroll
      for (int r = 0; r < 4; ++r) inv[qh][r] = 1.0f / Lp[qh][r];

    const float* xb = x + (size_t)b * CDIM * NTOK;
    float* ob = out + (size_t)b * CDIM * NTOK;
#pragma unroll
    for (int qh = 0; qh < 2; ++qh)
#pragma unroll
      for (int ct = 0; ct < 8; ++ct) {
        int c = ct * 16 + l15;
        size_t idx = (size_t)c * NTOK + q0 + qh * 16 + 4 * g;
        f32x4 xv = *(const f32x4*)&xb[idx];
        f32x4 o;
#pragma unroll
        for (int r = 0; r < 4; ++r)
          o[r] = ga * acc[qh * 8 + ct][r] * inv[qh][r] + xv[r];
        *(f32x4*)&ob[idx] = o;
      }
  }
}

extern "C" void kernel_launch(void* const* d_in, const int* in_sizes, int n_in,
                              void* d_out, int out_size, void* d_ws, size_t ws_size,
                              hipStream_t stream) {
  const float* x     = (const float*)d_in[0];
  const float* Wq    = (const float*)d_in[1];
  const float* bq    = (const float*)d_in[2];
  const float* Wk    = (const float*)d_in[3];
  const float* bk    = (const float*)d_in[4];
  const float* Wv    = (const float*)d_in[5];
  const float* bv    = (const float*)d_in[6];
  const float* gamma = (const float*)d_in[7];

  unsigned short* qb = (unsigned short*)d_ws;          // 512 KB
  unsigned short* kb = qb + (size_t)4 * NTOK * 16;     // 512 KB
  unsigned short* vb = kb + (size_t)4 * NTOK * 16;     // 4 MB (tiled layout)
  float* outp = (float*)d_out;

  sa3d_proj<<<dim3(256), dim3(256), 0, stream>>>(x, Wq, bq, Wk, bk, Wv, bv,
                                                 qb, kb, vb);
  sa3d_attn<<<dim3(512), dim3(512), 0, stream>>>(qb, kb, vb, x, gamma, outp);
}